// Round 4
// baseline (509.187 us; speedup 1.0000x reference)
//
#include <hip/hip_runtime.h>
#include <hip/hip_bf16.h>

#define C_   128
#define H_   120
#define W_   120
#define HW   14400
#define L_   14400
#define DIN  160
#define NST  24
#define RNK  8
#define NC   480
#define LC   30

// ---- weight-region offsets (floats) ----
#define OFF_NW    0
#define OFF_NB    128
#define OFF_WIN   256
#define OFF_CW    41216
#define OFF_CB    41856
#define OFF_WX    42016
#define OFF_WDT   50976
#define OFF_BDT   52256
#define OFF_AF    52416
#define OFF_DW    56256
#define OFF_WOUT  56416
#define OFF_FW    76896
#define OFF_SC    93280
#define OFF_WX2   93296      // 256x160 combined [Wdt@Wx[:8] ; Wx[8:56] ; zero-pad]
#define OFF_WG    134256     // 128x640 fused output weight
#define WF_TOTAL  216176

// ---- per-batch buffer offsets (floats), base = WF_TOTAL ----
#define PB_XT     0            // (HW,128) x-transpose (dead after LN); DLU overlays here
#define PB_SEQ    1843200      // (L,128) LN out (dead after EPI0 gemm)
#define PB_XM     3686400      // (L,160) xm raw (dead after conv)
#define PB_ZS     5990400      // (L,160) silu(z); scan2 overwrites with y in place
#define PB_UB     8294400      // (L,160) conv+silu out
#define PB_BM     10598400     // (L,24)
#define PB_CM     10944000     // (L,24)
#define PB_HB     11289600     // (NC,160,24) chunk h (local, then h_in)
#define PB_S      13132800     // (NC,160) per-chunk sum of delta
#define PB_DLU    0            // (L,160) float2 {delta,u} — overlays XT+SEQ+XM (all dead)
// total pb = 13209600 floats; ws = (216176+13209600)*4 ≈ 53.7 MB

static __device__ __forceinline__ bool sniff_bf16(const void* nw) {
    return ((*(const unsigned*)nw) & 0xFFFFu) == 0x3F80u;
}
static __device__ __forceinline__ float ldin(const void* p, size_t i, bool bf) {
    return bf ? __bfloat162float(((const __hip_bfloat16*)p)[i]) : ((const float*)p)[i];
}

// ---------------------------------------------------------------- convert all weights -> fp32 ws region
__global__ void k_cvtw(const void* nw, const void* nb_, const void* win, const void* cw,
                       const void* cb, const void* wx, const void* wdt, const void* bdt,
                       const void* alog, const void* dw, const void* wout, const void* fw,
                       const void* sc, float* __restrict__ wf) {
    int i = blockIdx.x * 256 + threadIdx.x;
    bool bf = sniff_bf16(nw);
    int j = i;
    if (j < 128)   { wf[OFF_NW  + j] = ldin(nw,  j, bf); return; } j -= 128;
    if (j < 128)   { wf[OFF_NB  + j] = ldin(nb_, j, bf); return; } j -= 128;
    if (j < 40960) { wf[OFF_WIN + j] = ldin(win, j, bf); return; } j -= 40960;
    if (j < 640)   { wf[OFF_CW  + j] = ldin(cw,  j, bf); return; } j -= 640;
    if (j < 160)   { wf[OFF_CB  + j] = ldin(cb,  j, bf); return; } j -= 160;
    if (j < 8960)  { wf[OFF_WX  + j] = ldin(wx,  j, bf); return; } j -= 8960;
    if (j < 1280)  { wf[OFF_WDT + j] = ldin(wdt, j, bf); return; } j -= 1280;
    if (j < 160)   { wf[OFF_BDT + j] = ldin(bdt, j, bf); return; } j -= 160;
    if (j < 3840)  { wf[OFF_AF  + j] = -__expf(ldin(alog, j, bf)); return; } j -= 3840;
    if (j < 160)   { wf[OFF_DW  + j] = ldin(dw,  j, bf); return; } j -= 160;
    if (j < 20480) { wf[OFF_WOUT+ j] = ldin(wout,j, bf); return; } j -= 20480;
    if (j < 16384) { wf[OFF_FW  + j] = ldin(fw,  j, bf); return; } j -= 16384;
    if (j < 1)     { wf[OFF_SC  + j] = ldin(sc,  j, bf); return; }
}

// ---------------------------------------------------------------- WX2 = [W_dt @ W_x[:8] ; W_x[8:56] ; zeros] (256x160)
__global__ void k_wcomb(float* __restrict__ wf) {
    int idx = blockIdx.x * 256 + threadIdx.x;
    if (idx >= 256 * 160) return;
    int row = idx / 160, j = idx % 160;
    float v = 0.f;
    if (row < 160) {
#pragma unroll
        for (int r = 0; r < 8; r++) v += wf[OFF_WDT + row * 8 + r] * wf[OFF_WX + r * 160 + j];
    } else if (row < 208) {
        v = wf[OFF_WX + (row - 152) * 160 + j];
    }
    wf[OFF_WX2 + idx] = v;
}

// ---------------------------------------------------------------- Wg[o, g*160+d] = sum_{j<32} fw[o, g*32+j] * Wout[g*32+j, d]
__global__ void k_wg(float* __restrict__ wf) {
    int idx = blockIdx.x * 256 + threadIdx.x;
    if (idx >= 128 * 640) return;
    int o = idx / 640, k = idx % 640;
    int g = k / 160, d = k % 160;
    float v = 0.f;
#pragma unroll
    for (int j = 0; j < 32; j++)
        v += wf[OFF_FW + o * 128 + g * 32 + j] * wf[OFF_WOUT + (g * 32 + j) * 160 + d];
    wf[OFF_WG + idx] = v;
}

// ---------------------------------------------------------------- transpose+convert x (C,HW) -> xT (HW,128) fp32, one batch
__global__ __launch_bounds__(1024) void k_trans(const void* __restrict__ x, const void* __restrict__ nw,
                                                float* __restrict__ xT, int b) {
    __shared__ float tile[32][33];
    bool bf = sniff_bf16(nw);
    int p0 = blockIdx.x * 32, c0 = blockIdx.y * 32;
    int tx = threadIdx.x, ty = threadIdx.y;
    size_t e = (size_t)(b * C_ + c0 + ty) * HW + p0 + tx;
    tile[ty][tx] = ldin(x, e, bf);
    __syncthreads();
    xT[(size_t)(p0 + ty) * C_ + c0 + tx] = tile[tx][ty];
}

// ---------------------------------------------------------------- gather + layernorm, wave per row (4 rows/block)
__global__ __launch_bounds__(256) void k_ln(const float* __restrict__ xT, const float* __restrict__ wf,
                                            float* __restrict__ seq) {
    int l = blockIdx.x * 4 + (threadIdx.x >> 6);
    int lane = threadIdx.x & 63;
    int pj = L_ - 1 - l;
    int pt = (l % H_) * W_ + (l / H_);
    int ptj = (pj % H_) * W_ + (pj / H_);
    int p0 = (lane < 32) ? l : pj;        // groups 0,1
    int p1 = (lane < 32) ? pt : ptj;      // groups 2,3
    float v0 = xT[(size_t)p0 * C_ + lane];
    float v1 = xT[(size_t)p1 * C_ + lane + 64];
    float s = v0 + v1, q = v0 * v0 + v1 * v1;
#pragma unroll
    for (int off = 32; off > 0; off >>= 1) {
        s += __shfl_xor(s, off);
        q += __shfl_xor(q, off);
    }
    float mu = s * (1.f / 128.f);
    float var = q * (1.f / 128.f) - mu * mu;
    float rs = rsqrtf(var + 1e-5f);
    seq[(size_t)l * C_ + lane]      = (v0 - mu) * rs * wf[OFF_NW + lane]      + wf[OFF_NB + lane];
    seq[(size_t)l * C_ + lane + 64] = (v1 - mu) * rs * wf[OFF_NW + lane + 64] + wf[OFF_NB + lane + 64];
}

// ---------------------------------------------------------------- tiled fp32 GEMM: out[m,n] = sum_k A[m,k]*W[n,k]
// EPI 0: n<160 -> out0 (xm raw), else out1 = silu (zs).
// EPI 1: n<160 -> dlu float2{softplus(v+bias[n]), u}; n<184 -> out1 (B); n<208 -> out2 (C).
template <int KTOT, int EPI>
__global__ __launch_bounds__(256) void k_gemm(const float* __restrict__ A,
                                              const float* __restrict__ Wt,
                                              float* __restrict__ out0,
                                              float* __restrict__ out1,
                                              float* __restrict__ out2,
                                              const float* __restrict__ bias) {
    __shared__ float As[32][68];
    __shared__ float Bs[32][68];
    int tx = threadIdx.x, ty = threadIdx.y;
    int t = ty * 16 + tx;
    int m0 = blockIdx.x * 64, n0 = blockIdx.y * 64;
    float acc[4][4] = {};
    int kc = (t & 7) * 4;
    int rr = t >> 3;
    for (int k0 = 0; k0 < KTOT; k0 += 32) {
#pragma unroll
        for (int r = 0; r < 2; r++) {
            int row = rr + r * 32;
            float4 a4 = *(const float4*)(A + (size_t)(m0 + row) * KTOT + k0 + kc);
            As[kc + 0][row] = a4.x; As[kc + 1][row] = a4.y;
            As[kc + 2][row] = a4.z; As[kc + 3][row] = a4.w;
        }
#pragma unroll
        for (int r = 0; r < 2; r++) {
            int n = rr + r * 32;
            float4 b4 = *(const float4*)(Wt + (size_t)(n0 + n) * KTOT + k0 + kc);
            Bs[kc + 0][n] = b4.x; Bs[kc + 1][n] = b4.y;
            Bs[kc + 2][n] = b4.z; Bs[kc + 3][n] = b4.w;
        }
        __syncthreads();
#pragma unroll
        for (int k = 0; k < 32; k++) {
            float4 a4 = *(const float4*)(&As[k][ty * 4]);
            float4 b4 = *(const float4*)(&Bs[k][tx * 4]);
            acc[0][0] += a4.x * b4.x; acc[0][1] += a4.x * b4.y; acc[0][2] += a4.x * b4.z; acc[0][3] += a4.x * b4.w;
            acc[1][0] += a4.y * b4.x; acc[1][1] += a4.y * b4.y; acc[1][2] += a4.y * b4.z; acc[1][3] += a4.y * b4.w;
            acc[2][0] += a4.z * b4.x; acc[2][1] += a4.z * b4.y; acc[2][2] += a4.z * b4.z; acc[2][3] += a4.z * b4.w;
            acc[3][0] += a4.w * b4.x; acc[3][1] += a4.w * b4.y; acc[3][2] += a4.w * b4.z; acc[3][3] += a4.w * b4.w;
        }
        __syncthreads();
    }
#pragma unroll
    for (int i = 0; i < 4; i++) {
#pragma unroll
        for (int j = 0; j < 4; j++) {
            int m = m0 + ty * 4 + i;
            int n = n0 + tx * 4 + j;
            float v = acc[i][j];
            if (EPI == 0) {
                if (n < 160) out0[(size_t)m * 160 + n] = v;
                else         out1[(size_t)m * 160 + (n - 160)] = v / (1.f + __expf(-v));
            } else {
                if (n < 160) {
                    float s = v + bias[n];
                    float dl = (s > 15.f) ? s : log1pf(__expf(s));
                    float uu = A[(size_t)m * KTOT + n];
                    ((float2*)out0)[(size_t)m * 160 + n] = make_float2(dl, uu);
                } else if (n < 184) out1[(size_t)m * 24 + (n - 160)] = v;
                else if (n < 208)   out2[(size_t)m * 24 + (n - 184)] = v;
            }
        }
    }
}

// ---------------------------------------------------------------- depthwise causal conv(4) + bias + silu (one batch)
__global__ void k_conv(const float* __restrict__ xm, const float* __restrict__ wf,
                       float* __restrict__ ub) {
    int idx = blockIdx.x * 256 + threadIdx.x;
    if (idx >= L_ * DIN) return;
    int d = idx % DIN;
    int l = idx / DIN;
    float acc = wf[OFF_CB + d];
#pragma unroll
    for (int k = 0; k < 4; k++) {
        int lo = l - 3 + k;
        if (lo >= 0) acc += wf[OFF_CW + d * 4 + k] * xm[(size_t)lo * DIN + d];
    }
    ub[idx] = acc / (1.f + __expf(-acc));
}

// ---------------------------------------------------------------- scan pass 1 (4-way split, software-pipelined)
// emits S = sum(delta) per (c,d) and chunk-local h
__global__ __launch_bounds__(256) void k_scan1(const float2* __restrict__ dlu,
                                               const float* __restrict__ Bm, const float* __restrict__ wf,
                                               float* __restrict__ S_arr, float* __restrict__ Hb) {
    int idx = blockIdx.x * 256 + threadIdx.x;   // NC*DIN*4 = 307200
    int hf = idx & 3;
    int d  = (idx >> 2) % DIN;
    int c  = idx / (DIN * 4);
    const float2* Ap = (const float2*)(wf + OFF_AF + d * NST + hf * 6);
    float2 a01 = Ap[0], a23 = Ap[1], a45 = Ap[2];
    float h0 = 0, h1 = 0, h2 = 0, h3 = 0, h4 = 0, h5 = 0, S = 0;
    int base0 = c * LC;
    float2 duc = dlu[(size_t)base0 * DIN + d];
    const float2* Bp = (const float2*)(Bm + (size_t)base0 * NST) + hf * 3;
    float2 b01c = Bp[0], b23c = Bp[1], b45c = Bp[2];
#pragma unroll
    for (int j = 0; j < LC; j++) {
        float2 dun, b01n, b23n, b45n;
        if (j + 1 < LC) {
            dun = dlu[(size_t)(base0 + j + 1) * DIN + d];
            const float2* Bq = (const float2*)(Bm + (size_t)(base0 + j + 1) * NST) + hf * 3;
            b01n = Bq[0]; b23n = Bq[1]; b45n = Bq[2];
        }
        float dl = duc.x, uu = duc.y, du = dl * uu;
        S += dl;
        h0 = fmaf(__expf(dl * a01.x), h0, du * b01c.x);
        h1 = fmaf(__expf(dl * a01.y), h1, du * b01c.y);
        h2 = fmaf(__expf(dl * a23.x), h2, du * b23c.x);
        h3 = fmaf(__expf(dl * a23.y), h3, du * b23c.y);
        h4 = fmaf(__expf(dl * a45.x), h4, du * b45c.x);
        h5 = fmaf(__expf(dl * a45.y), h5, du * b45c.y);
        duc = dun; b01c = b01n; b23c = b23n; b45c = b45n;
    }
    if (hf == 0) S_arr[c * DIN + d] = S;
    float2* hp = (float2*)(Hb + (size_t)(c * DIN + d) * NST + hf * 6);
    hp[0] = make_float2(h0, h1); hp[1] = make_float2(h2, h3); hp[2] = make_float2(h4, h5);
}

// ---------------------------------------------------------------- chunk-level scan (pipelined groups of 16); Hb[c] <- h_in
__global__ void k_chunkscan(const float* __restrict__ S_arr, const float* __restrict__ wf,
                            float* __restrict__ Hb) {
    int idx = blockIdx.x * 256 + threadIdx.x;   // DIN*NST = 3840
    if (idx >= DIN * NST) return;
    int d = idx / NST, n = idx % NST;
    float A = wf[OFF_AF + d * NST + n];
    float h = 0.f;
    float sc[16], qc[16];
#pragma unroll
    for (int j = 0; j < 16; j++) {
        sc[j] = S_arr[j * DIN + d];
        qc[j] = Hb[(size_t)(j * DIN + d) * NST + n];
    }
    for (int c0 = 0; c0 < NC; c0 += 16) {
        float sn[16], qn[16];
        if (c0 + 16 < NC) {
#pragma unroll
            for (int j = 0; j < 16; j++) {
                sn[j] = S_arr[(c0 + 16 + j) * DIN + d];
                qn[j] = Hb[(size_t)((c0 + 16 + j) * DIN + d) * NST + n];
            }
        }
#pragma unroll
        for (int j = 0; j < 16; j++) {
            Hb[(size_t)((c0 + j) * DIN + d) * NST + n] = h;
            h = fmaf(__expf(A * sc[j]), h, qc[j]);
        }
#pragma unroll
        for (int j = 0; j < 16; j++) { sc[j] = sn[j]; qc[j] = qn[j]; }
    }
}

// ---------------------------------------------------------------- scan pass 2 (4-way split, pipelined, shuffle-reduce y)
__global__ __launch_bounds__(256) void k_scan2(const float2* __restrict__ dlu,
                                               const float* __restrict__ Bm, const float* __restrict__ Cm,
                                               const float* __restrict__ wf, const float* __restrict__ Hb,
                                               float* __restrict__ zs_y) {
    int idx = blockIdx.x * 256 + threadIdx.x;   // 307200
    int hf = idx & 3;
    int d  = (idx >> 2) % DIN;
    int c  = idx / (DIN * 4);
    const float2* Ap = (const float2*)(wf + OFF_AF + d * NST + hf * 6);
    float2 a01 = Ap[0], a23 = Ap[1], a45 = Ap[2];
    const float2* Hp = (const float2*)(Hb + (size_t)(c * DIN + d) * NST + hf * 6);
    float2 h01 = Hp[0], h23 = Hp[1], h45 = Hp[2];
    float h0 = h01.x, h1 = h01.y, h2 = h23.x, h3 = h23.y, h4 = h45.x, h5 = h45.y;
    float Dd = wf[OFF_DW + d];
    int base0 = c * LC;
    float2 duc = dlu[(size_t)base0 * DIN + d];
    const float2* Bp = (const float2*)(Bm + (size_t)base0 * NST) + hf * 3;
    const float2* Cp = (const float2*)(Cm + (size_t)base0 * NST) + hf * 3;
    float2 b01c = Bp[0], b23c = Bp[1], b45c = Bp[2];
    float2 c01c = Cp[0], c23c = Cp[1], c45c = Cp[2];
#pragma unroll
    for (int j = 0; j < LC; j++) {
        float2 dun, b01n, b23n, b45n, c01n, c23n, c45n;
        if (j + 1 < LC) {
            dun = dlu[(size_t)(base0 + j + 1) * DIN + d];
            const float2* Bq = (const float2*)(Bm + (size_t)(base0 + j + 1) * NST) + hf * 3;
            const float2* Cq = (const float2*)(Cm + (size_t)(base0 + j + 1) * NST) + hf * 3;
            b01n = Bq[0]; b23n = Bq[1]; b45n = Bq[2];
            c01n = Cq[0]; c23n = Cq[1]; c45n = Cq[2];
        }
        float dl = duc.x, uu = duc.y, du = dl * uu;
        float y;
        h0 = fmaf(__expf(dl * a01.x), h0, du * b01c.x); y = h0 * c01c.x;
        h1 = fmaf(__expf(dl * a01.y), h1, du * b01c.y); y = fmaf(h1, c01c.y, y);
        h2 = fmaf(__expf(dl * a23.x), h2, du * b23c.x); y = fmaf(h2, c23c.x, y);
        h3 = fmaf(__expf(dl * a23.y), h3, du * b23c.y); y = fmaf(h3, c23c.y, y);
        h4 = fmaf(__expf(dl * a45.x), h4, du * b45c.x); y = fmaf(h4, c45c.x, y);
        h5 = fmaf(__expf(dl * a45.y), h5, du * b45c.y); y = fmaf(h5, c45c.y, y);
        y += __shfl_xor(y, 1);
        y += __shfl_xor(y, 2);
        if (hf == 0) {
            size_t zo = (size_t)(base0 + j) * DIN + d;
            zs_y[zo] = (y + uu * Dd) * zs_y[zo];
        }
        duc = dun; b01c = b01n; b23c = b23n; b45c = b45n; c01c = c01n; c23c = c23n; c45c = c45n;
    }
}

// ---------------------------------------------------------------- fused output: gathered GEMM (K=640, Wg) + residual -> out
__global__ __launch_bounds__(256) void k_fout(const float* __restrict__ y,
                                              const float* __restrict__ wf,
                                              const void* __restrict__ x,
                                              const void* __restrict__ nwraw,
                                              void* __restrict__ outp, int b) {
    __shared__ float As[32][68];
    __shared__ float Bs[32][68];
    bool bf = sniff_bf16(nwraw);
    int tx = threadIdx.x, ty = threadIdx.y;
    int t = ty * 16 + tx;
    int m0 = blockIdx.x * 64, n0 = blockIdx.y * 64;
    float acc[4][4] = {};
    int kc = (t & 7) * 4;
    int rr = t >> 3;
    for (int k0 = 0; k0 < 640; k0 += 32) {
        int g = k0 / 160;
        int db = (k0 % 160) + kc;
#pragma unroll
        for (int r = 0; r < 2; r++) {
            int row = rr + r * 32;
            int p = m0 + row;
            int hh = p / W_, ww = p % W_;
            int l;
            if (g == 0)      l = p;
            else if (g == 1) l = L_ - 1 - p;
            else if (g == 2) l = ww * H_ + hh;
            else             l = L_ - 1 - (ww * H_ + hh);
            float4 a4 = *(const float4*)(y + (size_t)l * DIN + db);
            As[kc + 0][row] = a4.x; As[kc + 1][row] = a4.y;
            As[kc + 2][row] = a4.z; As[kc + 3][row] = a4.w;
        }
#pragma unroll
        for (int r = 0; r < 2; r++) {
            int n = rr + r * 32;
            float4 b4 = *(const float4*)(wf + OFF_WG + (size_t)(n0 + n) * 640 + k0 + kc);
            Bs[kc + 0][n] = b4.x; Bs[kc + 1][n] = b4.y;
            Bs[kc + 2][n] = b4.z; Bs[kc + 3][n] = b4.w;
        }
        __syncthreads();
#pragma unroll
        for (int k = 0; k < 32; k++) {
            float4 a4 = *(const float4*)(&As[k][ty * 4]);
            float4 b4 = *(const float4*)(&Bs[k][tx * 4]);
            acc[0][0] += a4.x * b4.x; acc[0][1] += a4.x * b4.y; acc[0][2] += a4.x * b4.z; acc[0][3] += a4.x * b4.w;
            acc[1][0] += a4.y * b4.x; acc[1][1] += a4.y * b4.y; acc[1][2] += a4.y * b4.z; acc[1][3] += a4.y * b4.w;
            acc[2][0] += a4.z * b4.x; acc[2][1] += a4.z * b4.y; acc[2][2] += a4.z * b4.z; acc[2][3] += a4.z * b4.w;
            acc[3][0] += a4.w * b4.x; acc[3][1] += a4.w * b4.y; acc[3][2] += a4.w * b4.z; acc[3][3] += a4.w * b4.w;
        }
        __syncthreads();
    }
    float sc = wf[OFF_SC];
#pragma unroll
    for (int i = 0; i < 4; i++) {
#pragma unroll
        for (int j = 0; j < 4; j++) {
            int p = m0 + ty * 4 + i;
            int co = n0 + tx * 4 + j;
            size_t o = (size_t)(b * C_ + co) * HW + p;
            float res = sc * acc[i][j];
            if (bf) ((__hip_bfloat16*)outp)[o] = __float2bfloat16(
                        __bfloat162float(((const __hip_bfloat16*)x)[o]) + res);
            else    ((float*)outp)[o] = ((const float*)x)[o] + res;
        }
    }
}

// ----------------------------------------------------------------
extern "C" void kernel_launch(void* const* d_in, const int* in_sizes, int n_in,
                              void* d_out, int out_size, void* d_ws, size_t ws_size,
                              hipStream_t stream) {
    const void* x    = d_in[0];
    const void* nw   = d_in[1];
    const void* nb_  = d_in[2];
    const void* Win  = d_in[3];
    const void* cw   = d_in[4];
    const void* cb   = d_in[5];
    const void* Wx   = d_in[6];
    const void* Wdt  = d_in[7];
    const void* bdt  = d_in[8];
    const void* Alog = d_in[9];
    const void* Dw   = d_in[10];
    const void* Wout = d_in[11];
    const void* fw   = d_in[12];
    const void* sc   = d_in[13];
    (void)in_sizes; (void)n_in; (void)out_size; (void)ws_size;

    float* wf = (float*)d_ws;
    float* pb = wf + WF_TOTAL;
    float* xT  = pb + PB_XT;
    float* seq = pb + PB_SEQ;
    float* xm  = pb + PB_XM;
    float* zs  = pb + PB_ZS;
    float* ub  = pb + PB_UB;
    float* Bm  = pb + PB_BM;
    float* Cm  = pb + PB_CM;
    float* Hb  = pb + PB_HB;
    float* Sa  = pb + PB_S;
    float2* dlu = (float2*)(pb + PB_DLU);

    k_cvtw<<<365, 256, 0, stream>>>(nw, nb_, Win, cw, cb, Wx, Wdt, bdt, Alog, Dw, Wout, fw, sc, wf);
    k_wcomb<<<160, 256, 0, stream>>>(wf);
    k_wg<<<320, 256, 0, stream>>>(wf);

    for (int b = 0; b < 2; b++) {
        k_trans<<<dim3(HW / 32, C_ / 32), dim3(32, 32), 0, stream>>>(x, nw, xT, b);
        k_ln<<<3600, 256, 0, stream>>>(xT, wf, seq);
        k_gemm<128, 0><<<dim3(225, 5), dim3(16, 16), 0, stream>>>(seq, wf + OFF_WIN, xm, zs, nullptr, nullptr);
        k_conv<<<9000, 256, 0, stream>>>(xm, wf, ub);
        k_gemm<160, 1><<<dim3(225, 4), dim3(16, 16), 0, stream>>>(ub, wf + OFF_WX2, (float*)dlu, Bm, Cm, wf + OFF_BDT);
        k_scan1<<<1200, 256, 0, stream>>>(dlu, Bm, wf, Sa, Hb);
        k_chunkscan<<<15, 256, 0, stream>>>(Sa, wf, Hb);
        k_scan2<<<1200, 256, 0, stream>>>(dlu, Bm, Cm, wf, Hb, zs);
        k_fout<<<dim3(225, 2), dim3(16, 16), 0, stream>>>(zs, wf, x, nw, d_out, b);
    }
}

// Round 5
// 422.343 us; speedup vs baseline: 1.2056x; 1.2056x over previous
//
#include <hip/hip_runtime.h>
#include <hip/hip_bf16.h>

#define C_   128
#define H_   120
#define W_   120
#define HW   14400
#define L_   14400
#define DIN  160
#define NST  24
#define NC   480
#define LC   30

// ---- weight-region offsets (floats) ----
#define OFF_NW    0
#define OFF_NB    128
#define OFF_WIN   256
#define OFF_CW    41216
#define OFF_CB    41856
#define OFF_WX    42016
#define OFF_WDT   50976
#define OFF_BDT   52256
#define OFF_AF    52416
#define OFF_DW    56256
#define OFF_WOUT  56416
#define OFF_FW    76896
#define OFF_SC    93280
#define OFF_WX2   93296      // fp32 256x160 combined [Wdt@Wx[:8] ; Wx[8:56] ; zero-pad]
#define OFF_WG    134256     // fp32 128x640 fused output weight
#define OFF_WINB  216176     // bf16 320x128  (20480 floats)
#define OFF_WX2B  236656     // bf16 256x160  (20480 floats)
#define OFF_WGB   257136     // bf16 128x640  (40960 floats)
#define WF_TOTAL  298096

// ---- per-batch buffer offsets (floats), base = WF_TOTAL ----
#define PB_XT     0            // (HW,128) fp32 x-transpose (dead after LN)
#define PB_SEQ    1843200      // (L,128) bf16 LN out (dead after GEMM0)
#define PB_XM     2764800      // (L,160) fp32 xm raw (dead after conv)
#define PB_DLU    0            // (L,160) float2 {delta,u} — overlays XT+SEQ+XM (all dead by EPI1)
#define PB_ZS     5068800      // (L,160) fp32 silu(z)
#define PB_UB     7372800      // (L,160) bf16 conv+silu out
#define PB_BM     8524800      // (L,24) fp32
#define PB_CM     8870400      // (L,24) fp32
#define PB_HB     9216000      // (NC,160,24) fp32 chunk h
#define PB_S      11059200     // (NC,160) fp32 per-chunk sum of delta
#define PB_YB     11136000     // (L,160) bf16 gated y
// end = 12288000 floats; ws ≈ (298096+12288000)*4 ≈ 50.4 MB

typedef short bfrag __attribute__((ext_vector_type(8)));   // 8 bf16 (4 VGPRs)
typedef float ffrag __attribute__((ext_vector_type(4)));   // 4 fp32 acc

static __device__ __forceinline__ bool sniff_bf16(const void* nw) {
    return ((*(const unsigned*)nw) & 0xFFFFu) == 0x3F80u;
}
static __device__ __forceinline__ float ldin(const void* p, size_t i, bool bf) {
    return bf ? __bfloat162float(((const __hip_bfloat16*)p)[i]) : ((const float*)p)[i];
}
static __device__ __forceinline__ int gather_l(int p, int g) {
    if (g == 0) return p;
    if (g == 1) return L_ - 1 - p;
    int hh = p / W_, ww = p % W_;
    int t = ww * H_ + hh;
    return (g == 2) ? t : (L_ - 1 - t);
}

// ---------------------------------------------------------------- convert all weights -> fp32 ws region
__global__ void k_cvtw(const void* nw, const void* nb_, const void* win, const void* cw,
                       const void* cb, const void* wx, const void* wdt, const void* bdt,
                       const void* alog, const void* dw, const void* wout, const void* fw,
                       const void* sc, float* __restrict__ wf) {
    int i = blockIdx.x * 256 + threadIdx.x;
    bool bf = sniff_bf16(nw);
    int j = i;
    if (j < 128)   { wf[OFF_NW  + j] = ldin(nw,  j, bf); return; } j -= 128;
    if (j < 128)   { wf[OFF_NB  + j] = ldin(nb_, j, bf); return; } j -= 128;
    if (j < 40960) { wf[OFF_WIN + j] = ldin(win, j, bf); return; } j -= 40960;
    if (j < 640)   { wf[OFF_CW  + j] = ldin(cw,  j, bf); return; } j -= 640;
    if (j < 160)   { wf[OFF_CB  + j] = ldin(cb,  j, bf); return; } j -= 160;
    if (j < 8960)  { wf[OFF_WX  + j] = ldin(wx,  j, bf); return; } j -= 8960;
    if (j < 1280)  { wf[OFF_WDT + j] = ldin(wdt, j, bf); return; } j -= 1280;
    if (j < 160)   { wf[OFF_BDT + j] = ldin(bdt, j, bf); return; } j -= 160;
    if (j < 3840)  { wf[OFF_AF  + j] = -__expf(ldin(alog, j, bf)); return; } j -= 3840;
    if (j < 160)   { wf[OFF_DW  + j] = ldin(dw,  j, bf); return; } j -= 160;
    if (j < 20480) { wf[OFF_WOUT+ j] = ldin(wout,j, bf); return; } j -= 20480;
    if (j < 16384) { wf[OFF_FW  + j] = ldin(fw,  j, bf); return; } j -= 16384;
    if (j < 1)     { wf[OFF_SC  + j] = ldin(sc,  j, bf); return; }
}

// ---------------------------------------------------------------- WX2 = [W_dt @ W_x[:8] ; W_x[8:56] ; zeros] (256x160)
__global__ void k_wcomb(float* __restrict__ wf) {
    int idx = blockIdx.x * 256 + threadIdx.x;
    if (idx >= 256 * 160) return;
    int row = idx / 160, j = idx % 160;
    float v = 0.f;
    if (row < 160) {
#pragma unroll
        for (int r = 0; r < 8; r++) v += wf[OFF_WDT + row * 8 + r] * wf[OFF_WX + r * 160 + j];
    } else if (row < 208) {
        v = wf[OFF_WX + (row - 152) * 160 + j];
    }
    wf[OFF_WX2 + idx] = v;
}

// ---------------------------------------------------------------- Wg[o, g*160+d] = sum_{j<32} fw[o,g*32+j]*Wout[g*32+j,d]
__global__ void k_wg(float* __restrict__ wf) {
    int idx = blockIdx.x * 256 + threadIdx.x;
    if (idx >= 128 * 640) return;
    int o = idx / 640, k = idx % 640;
    int g = k / 160, d = k % 160;
    float v = 0.f;
#pragma unroll
    for (int j = 0; j < 32; j++)
        v += wf[OFF_FW + o * 128 + g * 32 + j] * wf[OFF_WOUT + (g * 32 + j) * 160 + d];
    wf[OFF_WG + idx] = v;
}

// ---------------------------------------------------------------- round GEMM weights fp32 -> bf16
__global__ void k_cvtb(float* __restrict__ wf) {
    int i = blockIdx.x * 256 + threadIdx.x;
    if (i < 40960) { ((__hip_bfloat16*)(wf + OFF_WINB))[i] = __float2bfloat16(wf[OFF_WIN + i]); return; }
    i -= 40960;
    if (i < 40960) { ((__hip_bfloat16*)(wf + OFF_WX2B))[i] = __float2bfloat16(wf[OFF_WX2 + i]); return; }
    i -= 40960;
    if (i < 81920) { ((__hip_bfloat16*)(wf + OFF_WGB))[i] = __float2bfloat16(wf[OFF_WG + i]); }
}

// ---------------------------------------------------------------- transpose+convert x (C,HW) -> xT (HW,128) fp32
__global__ __launch_bounds__(1024) void k_trans(const void* __restrict__ x, const void* __restrict__ nw,
                                                float* __restrict__ xT, int b) {
    __shared__ float tile[32][33];
    bool bf = sniff_bf16(nw);
    int p0 = blockIdx.x * 32, c0 = blockIdx.y * 32;
    int tx = threadIdx.x, ty = threadIdx.y;
    size_t e = (size_t)(b * C_ + c0 + ty) * HW + p0 + tx;
    tile[ty][tx] = ldin(x, e, bf);
    __syncthreads();
    xT[(size_t)(p0 + ty) * C_ + c0 + tx] = tile[tx][ty];
}

// ---------------------------------------------------------------- gather + layernorm -> seq bf16 (wave per row)
__global__ __launch_bounds__(256) void k_ln(const float* __restrict__ xT, const float* __restrict__ wf,
                                            __hip_bfloat16* __restrict__ seq) {
    int l = blockIdx.x * 4 + (threadIdx.x >> 6);
    int lane = threadIdx.x & 63;
    int pj = L_ - 1 - l;
    int pt = (l % H_) * W_ + (l / H_);
    int ptj = (pj % H_) * W_ + (pj / H_);
    int p0 = (lane < 32) ? l : pj;
    int p1 = (lane < 32) ? pt : ptj;
    float v0 = xT[(size_t)p0 * C_ + lane];
    float v1 = xT[(size_t)p1 * C_ + lane + 64];
    float s = v0 + v1, q = v0 * v0 + v1 * v1;
#pragma unroll
    for (int off = 32; off > 0; off >>= 1) {
        s += __shfl_xor(s, off);
        q += __shfl_xor(q, off);
    }
    float mu = s * (1.f / 128.f);
    float var = q * (1.f / 128.f) - mu * mu;
    float rs = rsqrtf(var + 1e-5f);
    seq[(size_t)l * C_ + lane]      = __float2bfloat16((v0 - mu) * rs * wf[OFF_NW + lane]      + wf[OFF_NB + lane]);
    seq[(size_t)l * C_ + lane + 64] = __float2bfloat16((v1 - mu) * rs * wf[OFF_NW + lane + 64] + wf[OFF_NB + lane + 64]);
}

// ---------------------------------------------------------------- MFMA bf16 GEMM, no LDS: wave = 32x64 tile
// EPI 0: n<160 -> xm fp32, else silu -> zs fp32
// EPI 1: n<160 -> dlu{softplus(v+bias),u}; [160,184) -> Bm; [184,208) -> Cm
// EPI 2: gathered A (scan-order y), D = sc*acc + x residual -> out
template <int KTOT, int EPI>
__global__ __launch_bounds__(128) void k_mgemm(const __hip_bfloat16* __restrict__ Ab,
                                               const __hip_bfloat16* __restrict__ Wb,
                                               float* __restrict__ out0, float* __restrict__ out1,
                                               float* __restrict__ out2, const float* __restrict__ bias,
                                               const __hip_bfloat16* __restrict__ ubp,
                                               const float* __restrict__ wf,
                                               const void* __restrict__ x, const void* __restrict__ nwraw,
                                               void* __restrict__ outp, int b) {
    int wv = threadIdx.x >> 6;
    int lane = threadIdx.x & 63;
    int l15 = lane & 15, quad = lane >> 4;
    int m0 = blockIdx.x * 64 + wv * 32;
    int n0 = blockIdx.y * 64;
    ffrag acc[2][4];
#pragma unroll
    for (int i = 0; i < 2; i++)
#pragma unroll
        for (int j = 0; j < 4; j++) acc[i][j] = (ffrag){0.f, 0.f, 0.f, 0.f};

    for (int k0 = 0; k0 < KTOT; k0 += 32) {
        bfrag a0, a1;
        if (EPI == 2) {
            int g = k0 / 160;
            int kk = (k0 % 160) + quad * 8;
            int l0 = gather_l(m0 + l15, g);
            int l1 = gather_l(m0 + 16 + l15, g);
            a0 = *(const bfrag*)(Ab + (size_t)l0 * 160 + kk);
            a1 = *(const bfrag*)(Ab + (size_t)l1 * 160 + kk);
        } else {
            int kb = k0 + quad * 8;
            a0 = *(const bfrag*)(Ab + (size_t)(m0 + l15) * KTOT + kb);
            a1 = *(const bfrag*)(Ab + (size_t)(m0 + 16 + l15) * KTOT + kb);
        }
        const __hip_bfloat16* wp = Wb + (size_t)(n0 + l15) * KTOT + k0 + quad * 8;
        bfrag b0 = *(const bfrag*)(wp);
        bfrag b1 = *(const bfrag*)(wp + (size_t)16 * KTOT);
        bfrag b2 = *(const bfrag*)(wp + (size_t)32 * KTOT);
        bfrag b3 = *(const bfrag*)(wp + (size_t)48 * KTOT);
        acc[0][0] = __builtin_amdgcn_mfma_f32_16x16x32_bf16(a0, b0, acc[0][0], 0, 0, 0);
        acc[0][1] = __builtin_amdgcn_mfma_f32_16x16x32_bf16(a0, b1, acc[0][1], 0, 0, 0);
        acc[0][2] = __builtin_amdgcn_mfma_f32_16x16x32_bf16(a0, b2, acc[0][2], 0, 0, 0);
        acc[0][3] = __builtin_amdgcn_mfma_f32_16x16x32_bf16(a0, b3, acc[0][3], 0, 0, 0);
        acc[1][0] = __builtin_amdgcn_mfma_f32_16x16x32_bf16(a1, b0, acc[1][0], 0, 0, 0);
        acc[1][1] = __builtin_amdgcn_mfma_f32_16x16x32_bf16(a1, b1, acc[1][1], 0, 0, 0);
        acc[1][2] = __builtin_amdgcn_mfma_f32_16x16x32_bf16(a1, b2, acc[1][2], 0, 0, 0);
        acc[1][3] = __builtin_amdgcn_mfma_f32_16x16x32_bf16(a1, b3, acc[1][3], 0, 0, 0);
    }

    bool bf = false;
    float sc = 0.f;
    if (EPI == 2) { bf = sniff_bf16(nwraw); sc = wf[OFF_SC]; }
#pragma unroll
    for (int fm = 0; fm < 2; fm++) {
#pragma unroll
        for (int fn = 0; fn < 4; fn++) {
            int n = n0 + fn * 16 + l15;
#pragma unroll
            for (int reg = 0; reg < 4; reg++) {
                int m = m0 + fm * 16 + quad * 4 + reg;
                float v = acc[fm][fn][reg];
                if (EPI == 0) {
                    if (n < 160) out0[(size_t)m * 160 + n] = v;
                    else         out1[(size_t)m * 160 + (n - 160)] = v / (1.f + __expf(-v));
                } else if (EPI == 1) {
                    if (n < 160) {
                        float s = v + bias[n];
                        float dl = (s > 15.f) ? s : log1pf(__expf(s));
                        float uu = __bfloat162float(ubp[(size_t)m * 160 + n]);
                        ((float2*)out0)[(size_t)m * 160 + n] = make_float2(dl, uu);
                    } else if (n < 184) out1[(size_t)m * 24 + (n - 160)] = v;
                    else if (n < 208)   out2[(size_t)m * 24 + (n - 184)] = v;
                } else {
                    size_t o = (size_t)(b * C_ + n) * HW + m;
                    float res = sc * v;
                    if (bf) ((__hip_bfloat16*)outp)[o] = __float2bfloat16(
                                __bfloat162float(((const __hip_bfloat16*)x)[o]) + res);
                    else    ((float*)outp)[o] = ((const float*)x)[o] + res;
                }
            }
        }
    }
}

// ---------------------------------------------------------------- depthwise causal conv(4) + bias + silu -> ub bf16
__global__ void k_conv(const float* __restrict__ xm, const float* __restrict__ wf,
                       __hip_bfloat16* __restrict__ ub) {
    int idx = blockIdx.x * 256 + threadIdx.x;
    if (idx >= L_ * DIN) return;
    int d = idx % DIN;
    int l = idx / DIN;
    float acc = wf[OFF_CB + d];
#pragma unroll
    for (int k = 0; k < 4; k++) {
        int lo = l - 3 + k;
        if (lo >= 0) acc += wf[OFF_CW + d * 4 + k] * xm[(size_t)lo * DIN + d];
    }
    ub[idx] = __float2bfloat16(acc / (1.f + __expf(-acc)));
}

// ---------------------------------------------------------------- scan pass 1 (4-way split, pipelined)
__global__ __launch_bounds__(256) void k_scan1(const float2* __restrict__ dlu,
                                               const float* __restrict__ Bm, const float* __restrict__ wf,
                                               float* __restrict__ S_arr, float* __restrict__ Hb) {
    int idx = blockIdx.x * 256 + threadIdx.x;   // NC*DIN*4
    int hf = idx & 3;
    int d  = (idx >> 2) % DIN;
    int c  = idx / (DIN * 4);
    const float2* Ap = (const float2*)(wf + OFF_AF + d * NST + hf * 6);
    float2 a01 = Ap[0], a23 = Ap[1], a45 = Ap[2];
    float h0 = 0, h1 = 0, h2 = 0, h3 = 0, h4 = 0, h5 = 0, S = 0;
    int base0 = c * LC;
    float2 duc = dlu[(size_t)base0 * DIN + d];
    const float2* Bp = (const float2*)(Bm + (size_t)base0 * NST) + hf * 3;
    float2 b01c = Bp[0], b23c = Bp[1], b45c = Bp[2];
#pragma unroll
    for (int j = 0; j < LC; j++) {
        float2 dun, b01n, b23n, b45n;
        if (j + 1 < LC) {
            dun = dlu[(size_t)(base0 + j + 1) * DIN + d];
            const float2* Bq = (const float2*)(Bm + (size_t)(base0 + j + 1) * NST) + hf * 3;
            b01n = Bq[0]; b23n = Bq[1]; b45n = Bq[2];
        }
        float dl = duc.x, uu = duc.y, du = dl * uu;
        S += dl;
        h0 = fmaf(__expf(dl * a01.x), h0, du * b01c.x);
        h1 = fmaf(__expf(dl * a01.y), h1, du * b01c.y);
        h2 = fmaf(__expf(dl * a23.x), h2, du * b23c.x);
        h3 = fmaf(__expf(dl * a23.y), h3, du * b23c.y);
        h4 = fmaf(__expf(dl * a45.x), h4, du * b45c.x);
        h5 = fmaf(__expf(dl * a45.y), h5, du * b45c.y);
        duc = dun; b01c = b01n; b23c = b23n; b45c = b45n;
    }
    if (hf == 0) S_arr[c * DIN + d] = S;
    float2* hp = (float2*)(Hb + (size_t)(c * DIN + d) * NST + hf * 6);
    hp[0] = make_float2(h0, h1); hp[1] = make_float2(h2, h3); hp[2] = make_float2(h4, h5);
}

// ---------------------------------------------------------------- chunk-level scan; Hb[c] <- h_in
__global__ void k_chunkscan(const float* __restrict__ S_arr, const float* __restrict__ wf,
                            float* __restrict__ Hb) {
    int idx = blockIdx.x * 256 + threadIdx.x;
    if (idx >= DIN * NST) return;
    int d = idx / NST, n = idx % NST;
    float A = wf[OFF_AF + d * NST + n];
    float h = 0.f;
    float sc[16], qc[16];
#pragma unroll
    for (int j = 0; j < 16; j++) {
        sc[j] = S_arr[j * DIN + d];
        qc[j] = Hb[(size_t)(j * DIN + d) * NST + n];
    }
    for (int c0 = 0; c0 < NC; c0 += 16) {
        float sn[16], qn[16];
        if (c0 + 16 < NC) {
#pragma unroll
            for (int j = 0; j < 16; j++) {
                sn[j] = S_arr[(c0 + 16 + j) * DIN + d];
                qn[j] = Hb[(size_t)((c0 + 16 + j) * DIN + d) * NST + n];
            }
        }
#pragma unroll
        for (int j = 0; j < 16; j++) {
            Hb[(size_t)((c0 + j) * DIN + d) * NST + n] = h;
            h = fmaf(__expf(A * sc[j]), h, qc[j]);
        }
#pragma unroll
        for (int j = 0; j < 16; j++) { sc[j] = sn[j]; qc[j] = qn[j]; }
    }
}

// ---------------------------------------------------------------- scan pass 2 -> yb bf16
__global__ __launch_bounds__(256) void k_scan2(const float2* __restrict__ dlu,
                                               const float* __restrict__ Bm, const float* __restrict__ Cm,
                                               const float* __restrict__ wf, const float* __restrict__ Hb,
                                               const float* __restrict__ zs, __hip_bfloat16* __restrict__ yb) {
    int idx = blockIdx.x * 256 + threadIdx.x;
    int hf = idx & 3;
    int d  = (idx >> 2) % DIN;
    int c  = idx / (DIN * 4);
    const float2* Ap = (const float2*)(wf + OFF_AF + d * NST + hf * 6);
    float2 a01 = Ap[0], a23 = Ap[1], a45 = Ap[2];
    const float2* Hp = (const float2*)(Hb + (size_t)(c * DIN + d) * NST + hf * 6);
    float2 h01 = Hp[0], h23 = Hp[1], h45 = Hp[2];
    float h0 = h01.x, h1 = h01.y, h2 = h23.x, h3 = h23.y, h4 = h45.x, h5 = h45.y;
    float Dd = wf[OFF_DW + d];
    int base0 = c * LC;
    float2 duc = dlu[(size_t)base0 * DIN + d];
    const float2* Bp = (const float2*)(Bm + (size_t)base0 * NST) + hf * 3;
    const float2* Cp = (const float2*)(Cm + (size_t)base0 * NST) + hf * 3;
    float2 b01c = Bp[0], b23c = Bp[1], b45c = Bp[2];
    float2 c01c = Cp[0], c23c = Cp[1], c45c = Cp[2];
#pragma unroll
    for (int j = 0; j < LC; j++) {
        float2 dun, b01n, b23n, b45n, c01n, c23n, c45n;
        if (j + 1 < LC) {
            dun = dlu[(size_t)(base0 + j + 1) * DIN + d];
            const float2* Bq = (const float2*)(Bm + (size_t)(base0 + j + 1) * NST) + hf * 3;
            const float2* Cq = (const float2*)(Cm + (size_t)(base0 + j + 1) * NST) + hf * 3;
            b01n = Bq[0]; b23n = Bq[1]; b45n = Bq[2];
            c01n = Cq[0]; c23n = Cq[1]; c45n = Cq[2];
        }
        float dl = duc.x, uu = duc.y, du = dl * uu;
        float y;
        h0 = fmaf(__expf(dl * a01.x), h0, du * b01c.x); y = h0 * c01c.x;
        h1 = fmaf(__expf(dl * a01.y), h1, du * b01c.y); y = fmaf(h1, c01c.y, y);
        h2 = fmaf(__expf(dl * a23.x), h2, du * b23c.x); y = fmaf(h2, c23c.x, y);
        h3 = fmaf(__expf(dl * a23.y), h3, du * b23c.y); y = fmaf(h3, c23c.y, y);
        h4 = fmaf(__expf(dl * a45.x), h4, du * b45c.x); y = fmaf(h4, c45c.x, y);
        h5 = fmaf(__expf(dl * a45.y), h5, du * b45c.y); y = fmaf(h5, c45c.y, y);
        y += __shfl_xor(y, 1);
        y += __shfl_xor(y, 2);
        if (hf == 0) {
            size_t zo = (size_t)(base0 + j) * DIN + d;
            yb[zo] = __float2bfloat16((y + uu * Dd) * zs[zo]);
        }
        duc = dun; b01c = b01n; b23c = b23n; b45c = b45n; c01c = c01n; c23c = c23n; c45c = c45n;
    }
}

// ----------------------------------------------------------------
extern "C" void kernel_launch(void* const* d_in, const int* in_sizes, int n_in,
                              void* d_out, int out_size, void* d_ws, size_t ws_size,
                              hipStream_t stream) {
    const void* x    = d_in[0];
    const void* nw   = d_in[1];
    const void* nb_  = d_in[2];
    const void* Win  = d_in[3];
    const void* cw   = d_in[4];
    const void* cb   = d_in[5];
    const void* Wx   = d_in[6];
    const void* Wdt  = d_in[7];
    const void* bdt  = d_in[8];
    const void* Alog = d_in[9];
    const void* Dw   = d_in[10];
    const void* Wout = d_in[11];
    const void* fw   = d_in[12];
    const void* sc   = d_in[13];
    (void)in_sizes; (void)n_in; (void)out_size; (void)ws_size;

    float* wf = (float*)d_ws;
    float* pb = wf + WF_TOTAL;
    float* xT  = pb + PB_XT;
    __hip_bfloat16* seq = (__hip_bfloat16*)(pb + PB_SEQ);
    float* xm  = pb + PB_XM;
    float2* dlu = (float2*)(pb + PB_DLU);
    float* zs  = pb + PB_ZS;
    __hip_bfloat16* ub = (__hip_bfloat16*)(pb + PB_UB);
    float* Bm  = pb + PB_BM;
    float* Cm  = pb + PB_CM;
    float* Hb  = pb + PB_HB;
    float* Sa  = pb + PB_S;
    __hip_bfloat16* yb = (__hip_bfloat16*)(pb + PB_YB);

    const __hip_bfloat16* winb = (const __hip_bfloat16*)(wf + OFF_WINB);
    const __hip_bfloat16* wx2b = (const __hip_bfloat16*)(wf + OFF_WX2B);
    const __hip_bfloat16* wgb  = (const __hip_bfloat16*)(wf + OFF_WGB);

    k_cvtw<<<365, 256, 0, stream>>>(nw, nb_, Win, cw, cb, Wx, Wdt, bdt, Alog, Dw, Wout, fw, sc, wf);
    k_wcomb<<<160, 256, 0, stream>>>(wf);
    k_wg<<<320, 256, 0, stream>>>(wf);
    k_cvtb<<<640, 256, 0, stream>>>(wf);

    for (int b = 0; b < 2; b++) {
        k_trans<<<dim3(HW / 32, C_ / 32), dim3(32, 32), 0, stream>>>(x, nw, xT, b);
        k_ln<<<3600, 256, 0, stream>>>(xT, wf, seq);
        k_mgemm<128, 0><<<dim3(225, 5), 128, 0, stream>>>(seq, winb, xm, zs, nullptr, nullptr,
                                                          nullptr, wf, nullptr, nullptr, nullptr, b);
        k_conv<<<9000, 256, 0, stream>>>(xm, wf, ub);
        k_mgemm<160, 1><<<dim3(225, 4), 128, 0, stream>>>(ub, wx2b, (float*)dlu, Bm, Cm, wf + OFF_BDT,
                                                          ub, wf, nullptr, nullptr, nullptr, b);
        k_scan1<<<1200, 256, 0, stream>>>(dlu, Bm, wf, Sa, Hb);
        k_chunkscan<<<15, 256, 0, stream>>>(Sa, wf, Hb);
        k_scan2<<<1200, 256, 0, stream>>>(dlu, Bm, Cm, wf, Hb, zs, yb);
        k_mgemm<640, 2><<<dim3(225, 2), 128, 0, stream>>>(yb, wgb, nullptr, nullptr, nullptr, nullptr,
                                                          nullptr, wf, x, nw, d_out, b);
    }
}

// Round 6
// 347.034 us; speedup vs baseline: 1.4673x; 1.2170x over previous
//
#include <hip/hip_runtime.h>
#include <hip/hip_bf16.h>

#define C_   128
#define H_   120
#define W_   120
#define HW   14400
#define L_   14400
#define DIN  160
#define NST  24
#define NC   480
#define LC   30

// ---- weight-region offsets (floats) ----
#define OFF_NW    0
#define OFF_NB    128
#define OFF_WIN   256
#define OFF_CW    41216
#define OFF_CB    41856
#define OFF_WX    42016
#define OFF_WDT   50976
#define OFF_BDT   52256
#define OFF_AF    52416
#define OFF_DW    56256
#define OFF_WOUT  56416
#define OFF_FW    76896
#define OFF_SC    93280
#define OFF_WX2   93296      // fp32 256x160 combined [Wdt@Wx[:8] ; Wx[8:56] ; zero-pad]
#define OFF_WG    134256     // fp32 128x640 fused output weight
#define OFF_WINB  216176     // bf16 320x128
#define OFF_WX2B  236656     // bf16 256x160
#define OFF_WGB   257136     // bf16 128x640
#define WF_TOTAL  298096

// ---- per-batch buffer offsets (float units), base = WF_TOTAL + b*PBSZ ----
#define PB_XT     0            // bf16 (HW,128)
#define PB_SEQ    921600       // bf16 (L,128)
#define PB_XM     1843200      // bf16 (L,160)
#define PB_ZS     2995200      // bf16 (L,160) silu(z)
#define PB_UB     4147200      // bf16 (L,160) conv+silu
#define PB_DLU    5299200      // uint (L,160) packed {bf16 delta, bf16 u}
#define PB_BM     7603200      // fp32 (L,24)
#define PB_CM     7948800      // fp32 (L,24)
#define PB_HB     8294400      // fp32 (NC,160,24)
#define PB_S      10137600     // fp32 (NC,160)
#define PB_YB     10214400     // bf16 (L,160) gated y
#define PBSZ      11366400
// total ws = (298096 + 2*11366400)*4 ≈ 92.1 MB  (ws_size ≈ 256 MiB)

typedef short bfrag __attribute__((ext_vector_type(8)));   // 8 bf16 (4 VGPRs)
typedef float ffrag __attribute__((ext_vector_type(4)));   // 4 fp32 acc

static __device__ __forceinline__ bool sniff_bf16(const void* nw) {
    return ((*(const unsigned*)nw) & 0xFFFFu) == 0x3F80u;
}
static __device__ __forceinline__ float ldin(const void* p, size_t i, bool bf) {
    return bf ? __bfloat162float(((const __hip_bfloat16*)p)[i]) : ((const float*)p)[i];
}
static __device__ __forceinline__ float us2f(unsigned short s) {
    unsigned u = ((unsigned)s) << 16;
    return __uint_as_float(u);
}
static __device__ __forceinline__ unsigned short f2us(float f) {
    __hip_bfloat16 h = __float2bfloat16(f);
    return *reinterpret_cast<unsigned short*>(&h);
}
static __device__ __forceinline__ int gather_l(int p, int g) {
    if (g == 0) return p;
    if (g == 1) return L_ - 1 - p;
    int hh = p / W_, ww = p % W_;
    int t = ww * H_ + hh;
    return (g == 2) ? t : (L_ - 1 - t);
}

// ---------------------------------------------------------------- weights -> fp32 ws region
__global__ void k_cvtw(const void* nw, const void* nb_, const void* win, const void* cw,
                       const void* cb, const void* wx, const void* wdt, const void* bdt,
                       const void* alog, const void* dw, const void* wout, const void* fw,
                       const void* sc, float* __restrict__ wf) {
    int i = blockIdx.x * 256 + threadIdx.x;
    bool bf = sniff_bf16(nw);
    int j = i;
    if (j < 128)   { wf[OFF_NW  + j] = ldin(nw,  j, bf); return; } j -= 128;
    if (j < 128)   { wf[OFF_NB  + j] = ldin(nb_, j, bf); return; } j -= 128;
    if (j < 40960) { wf[OFF_WIN + j] = ldin(win, j, bf); return; } j -= 40960;
    if (j < 640)   { wf[OFF_CW  + j] = ldin(cw,  j, bf); return; } j -= 640;
    if (j < 160)   { wf[OFF_CB  + j] = ldin(cb,  j, bf); return; } j -= 160;
    if (j < 8960)  { wf[OFF_WX  + j] = ldin(wx,  j, bf); return; } j -= 8960;
    if (j < 1280)  { wf[OFF_WDT + j] = ldin(wdt, j, bf); return; } j -= 1280;
    if (j < 160)   { wf[OFF_BDT + j] = ldin(bdt, j, bf); return; } j -= 160;
    if (j < 3840)  { wf[OFF_AF  + j] = -__expf(ldin(alog, j, bf)); return; } j -= 3840;
    if (j < 160)   { wf[OFF_DW  + j] = ldin(dw,  j, bf); return; } j -= 160;
    if (j < 20480) { wf[OFF_WOUT+ j] = ldin(wout,j, bf); return; } j -= 20480;
    if (j < 16384) { wf[OFF_FW  + j] = ldin(fw,  j, bf); return; } j -= 16384;
    if (j < 1)     { wf[OFF_SC  + j] = ldin(sc,  j, bf); return; }
}

// ---------------------------------------------------------------- WX2 = [W_dt @ W_x[:8] ; W_x[8:56] ; zeros]
__global__ void k_wcomb(float* __restrict__ wf) {
    int idx = blockIdx.x * 256 + threadIdx.x;
    if (idx >= 256 * 160) return;
    int row = idx / 160, j = idx % 160;
    float v = 0.f;
    if (row < 160) {
#pragma unroll
        for (int r = 0; r < 8; r++) v += wf[OFF_WDT + row * 8 + r] * wf[OFF_WX + r * 160 + j];
    } else if (row < 208) {
        v = wf[OFF_WX + (row - 152) * 160 + j];
    }
    wf[OFF_WX2 + idx] = v;
}

// ---------------------------------------------------------------- Wg[o, g*160+d] = sum_j fw[o,g*32+j]*Wout[g*32+j,d]
__global__ void k_wg(float* __restrict__ wf) {
    int idx = blockIdx.x * 256 + threadIdx.x;
    if (idx >= 128 * 640) return;
    int o = idx / 640, k = idx % 640;
    int g = k / 160, d = k % 160;
    float v = 0.f;
#pragma unroll
    for (int j = 0; j < 32; j++)
        v += wf[OFF_FW + o * 128 + g * 32 + j] * wf[OFF_WOUT + (g * 32 + j) * 160 + d];
    wf[OFF_WG + idx] = v;
}

// ---------------------------------------------------------------- GEMM weights fp32 -> bf16
__global__ void k_cvtb(float* __restrict__ wf) {
    int i = blockIdx.x * 256 + threadIdx.x;
    if (i < 40960) { ((__hip_bfloat16*)(wf + OFF_WINB))[i] = __float2bfloat16(wf[OFF_WIN + i]); return; }
    i -= 40960;
    if (i < 40960) { ((__hip_bfloat16*)(wf + OFF_WX2B))[i] = __float2bfloat16(wf[OFF_WX2 + i]); return; }
    i -= 40960;
    if (i < 81920) { ((__hip_bfloat16*)(wf + OFF_WGB))[i] = __float2bfloat16(wf[OFF_WG + i]); }
}

// ---------------------------------------------------------------- transpose x (C,HW) -> xT (HW,128) bf16, both batches
__global__ __launch_bounds__(1024) void k_trans(const void* __restrict__ x, const void* __restrict__ nw,
                                                float* __restrict__ pb) {
    __shared__ float tile[32][33];
    bool bf = sniff_bf16(nw);
    int b = blockIdx.z;
    __hip_bfloat16* xT = (__hip_bfloat16*)(pb + (size_t)b * PBSZ + PB_XT);
    int p0 = blockIdx.x * 32, c0 = blockIdx.y * 32;
    int tx = threadIdx.x, ty = threadIdx.y;
    size_t e = (size_t)(b * C_ + c0 + ty) * HW + p0 + tx;
    tile[ty][tx] = ldin(x, e, bf);
    __syncthreads();
    xT[(size_t)(p0 + ty) * C_ + c0 + tx] = __float2bfloat16(tile[tx][ty]);
}

// ---------------------------------------------------------------- gather + layernorm -> seq bf16 (wave per row)
__global__ __launch_bounds__(256) void k_ln(float* __restrict__ pb, const float* __restrict__ wf) {
    int b = blockIdx.z;
    const __hip_bfloat16* xT = (const __hip_bfloat16*)(pb + (size_t)b * PBSZ + PB_XT);
    __hip_bfloat16* seq = (__hip_bfloat16*)(pb + (size_t)b * PBSZ + PB_SEQ);
    int l = blockIdx.x * 4 + (threadIdx.x >> 6);
    int lane = threadIdx.x & 63;
    int pj = L_ - 1 - l;
    int pt = (l % H_) * W_ + (l / H_);
    int ptj = (pj % H_) * W_ + (pj / H_);
    int p0 = (lane < 32) ? l : pj;
    int p1 = (lane < 32) ? pt : ptj;
    float v0 = __bfloat162float(xT[(size_t)p0 * C_ + lane]);
    float v1 = __bfloat162float(xT[(size_t)p1 * C_ + lane + 64]);
    float s = v0 + v1, q = v0 * v0 + v1 * v1;
#pragma unroll
    for (int off = 32; off > 0; off >>= 1) {
        s += __shfl_xor(s, off);
        q += __shfl_xor(q, off);
    }
    float mu = s * (1.f / 128.f);
    float var = q * (1.f / 128.f) - mu * mu;
    float rs = rsqrtf(var + 1e-5f);
    seq[(size_t)l * C_ + lane]      = __float2bfloat16((v0 - mu) * rs * wf[OFF_NW + lane]      + wf[OFF_NB + lane]);
    seq[(size_t)l * C_ + lane + 64] = __float2bfloat16((v1 - mu) * rs * wf[OFF_NW + lane + 64] + wf[OFF_NB + lane + 64]);
}

// ---------------------------------------------------------------- MFMA bf16 GEMM, no LDS, wave = 32x64, batched (z)
// EPI 0: seq @ Win -> xm bf16 (n<160), silu -> zs bf16
// EPI 1: ub @ WX2 -> dlu packed (n<160), Bm fp32, Cm fp32
// EPI 2: gathered yb @ Wg -> out = x + sc*acc
template <int KTOT, int EPI>
__global__ __launch_bounds__(128) void k_mgemm(float* __restrict__ pb, const float* __restrict__ wf,
                                               const void* __restrict__ x, const void* __restrict__ nwraw,
                                               void* __restrict__ outp) {
    int b = blockIdx.z;
    float* base = pb + (size_t)b * PBSZ;
    const __hip_bfloat16* Ab;
    const __hip_bfloat16* Wb;
    if (EPI == 0)      { Ab = (const __hip_bfloat16*)(base + PB_SEQ); Wb = (const __hip_bfloat16*)(wf + OFF_WINB); }
    else if (EPI == 1) { Ab = (const __hip_bfloat16*)(base + PB_UB);  Wb = (const __hip_bfloat16*)(wf + OFF_WX2B); }
    else               { Ab = (const __hip_bfloat16*)(base + PB_YB);  Wb = (const __hip_bfloat16*)(wf + OFF_WGB); }

    int wv = threadIdx.x >> 6;
    int lane = threadIdx.x & 63;
    int l15 = lane & 15, quad = lane >> 4;
    int m0 = blockIdx.x * 64 + wv * 32;
    int n0 = blockIdx.y * 64;
    ffrag acc[2][4];
#pragma unroll
    for (int i = 0; i < 2; i++)
#pragma unroll
        for (int j = 0; j < 4; j++) acc[i][j] = (ffrag){0.f, 0.f, 0.f, 0.f};

    const int AST = (EPI == 2) ? 160 : KTOT;
    for (int k0 = 0; k0 < KTOT; k0 += 32) {
        bfrag a0, a1;
        if (EPI == 2) {
            int g = k0 / 160;
            int kk = (k0 % 160) + quad * 8;
            int l0 = gather_l(m0 + l15, g);
            int l1 = gather_l(m0 + 16 + l15, g);
            a0 = *(const bfrag*)(Ab + (size_t)l0 * AST + kk);
            a1 = *(const bfrag*)(Ab + (size_t)l1 * AST + kk);
        } else {
            int kb = k0 + quad * 8;
            a0 = *(const bfrag*)(Ab + (size_t)(m0 + l15) * AST + kb);
            a1 = *(const bfrag*)(Ab + (size_t)(m0 + 16 + l15) * AST + kb);
        }
        const __hip_bfloat16* wp = Wb + (size_t)(n0 + l15) * KTOT + k0 + quad * 8;
        bfrag b0 = *(const bfrag*)(wp);
        bfrag b1 = *(const bfrag*)(wp + (size_t)16 * KTOT);
        bfrag b2 = *(const bfrag*)(wp + (size_t)32 * KTOT);
        bfrag b3 = *(const bfrag*)(wp + (size_t)48 * KTOT);
        acc[0][0] = __builtin_amdgcn_mfma_f32_16x16x32_bf16(a0, b0, acc[0][0], 0, 0, 0);
        acc[0][1] = __builtin_amdgcn_mfma_f32_16x16x32_bf16(a0, b1, acc[0][1], 0, 0, 0);
        acc[0][2] = __builtin_amdgcn_mfma_f32_16x16x32_bf16(a0, b2, acc[0][2], 0, 0, 0);
        acc[0][3] = __builtin_amdgcn_mfma_f32_16x16x32_bf16(a0, b3, acc[0][3], 0, 0, 0);
        acc[1][0] = __builtin_amdgcn_mfma_f32_16x16x32_bf16(a1, b0, acc[1][0], 0, 0, 0);
        acc[1][1] = __builtin_amdgcn_mfma_f32_16x16x32_bf16(a1, b1, acc[1][1], 0, 0, 0);
        acc[1][2] = __builtin_amdgcn_mfma_f32_16x16x32_bf16(a1, b2, acc[1][2], 0, 0, 0);
        acc[1][3] = __builtin_amdgcn_mfma_f32_16x16x32_bf16(a1, b3, acc[1][3], 0, 0, 0);
    }

    __hip_bfloat16* xmp = (__hip_bfloat16*)(base + PB_XM);
    __hip_bfloat16* zsp = (__hip_bfloat16*)(base + PB_ZS);
    unsigned* dlup = (unsigned*)(base + PB_DLU);
    float* Bmp = base + PB_BM;
    float* Cmp = base + PB_CM;
    const unsigned short* ubu = (const unsigned short*)(base + PB_UB);
    const float* bias = wf + OFF_BDT;
    bool bf = false;
    float sc = 0.f;
    if (EPI == 2) { bf = sniff_bf16(nwraw); sc = wf[OFF_SC]; }
#pragma unroll
    for (int fm = 0; fm < 2; fm++) {
#pragma unroll
        for (int fn = 0; fn < 4; fn++) {
            int n = n0 + fn * 16 + l15;
#pragma unroll
            for (int reg = 0; reg < 4; reg++) {
                int m = m0 + fm * 16 + quad * 4 + reg;
                float v = acc[fm][fn][reg];
                if (EPI == 0) {
                    if (n < 160) xmp[(size_t)m * 160 + n] = __float2bfloat16(v);
                    else         zsp[(size_t)m * 160 + (n - 160)] = __float2bfloat16(v / (1.f + __expf(-v)));
                } else if (EPI == 1) {
                    if (n < 160) {
                        float s = v + bias[n];
                        float dl = (s > 15.f) ? s : log1pf(__expf(s));
                        unsigned ub16 = ubu[(size_t)m * 160 + n];
                        dlup[(size_t)m * 160 + n] = (unsigned)f2us(dl) | (ub16 << 16);
                    } else if (n < 184) Bmp[(size_t)m * 24 + (n - 160)] = v;
                    else if (n < 208)   Cmp[(size_t)m * 24 + (n - 184)] = v;
                } else {
                    size_t o = (size_t)(b * C_ + n) * HW + m;
                    float res = sc * v;
                    if (bf) ((__hip_bfloat16*)outp)[o] = __float2bfloat16(
                                __bfloat162float(((const __hip_bfloat16*)x)[o]) + res);
                    else    ((float*)outp)[o] = ((const float*)x)[o] + res;
                }
            }
        }
    }
}

// ---------------------------------------------------------------- depthwise causal conv(4) + bias + silu (batched)
__global__ void k_conv(float* __restrict__ pb, const float* __restrict__ wf) {
    int idx = blockIdx.x * 256 + threadIdx.x;     // 2*L*DIN
    int b = idx / (L_ * DIN);
    int r = idx - b * (L_ * DIN);
    int d = r % DIN;
    int l = r / DIN;
    const __hip_bfloat16* xm = (const __hip_bfloat16*)(pb + (size_t)b * PBSZ + PB_XM);
    __hip_bfloat16* ub = (__hip_bfloat16*)(pb + (size_t)b * PBSZ + PB_UB);
    float acc = wf[OFF_CB + d];
#pragma unroll
    for (int k = 0; k < 4; k++) {
        int lo = l - 3 + k;
        if (lo >= 0) acc += wf[OFF_CW + d * 4 + k] * __bfloat162float(xm[(size_t)lo * DIN + d]);
    }
    ub[r] = __float2bfloat16(acc / (1.f + __expf(-acc)));
}

// ---------------------------------------------------------------- scan pass 1 (4-way state split, pipelined, batched)
__global__ __launch_bounds__(256) void k_scan1(float* __restrict__ pb, const float* __restrict__ wf) {
    int idx = blockIdx.x * 256 + threadIdx.x;     // 2 * NC*DIN*4 = 614400
    int b = idx / (NC * DIN * 4);
    int r = idx - b * (NC * DIN * 4);
    int hf = r & 3;
    int d  = (r >> 2) % DIN;
    int c  = r / (DIN * 4);
    float* base = pb + (size_t)b * PBSZ;
    const unsigned* dlu = (const unsigned*)(base + PB_DLU);
    const float* Bm = base + PB_BM;
    float* S_arr = base + PB_S;
    float* Hb = base + PB_HB;

    const float2* Ap = (const float2*)(wf + OFF_AF + d * NST + hf * 6);
    float2 a01 = Ap[0], a23 = Ap[1], a45 = Ap[2];
    float h0 = 0, h1 = 0, h2 = 0, h3 = 0, h4 = 0, h5 = 0, S = 0;
    int base0 = c * LC;
    unsigned duc = dlu[(size_t)base0 * DIN + d];
    const float2* Bp = (const float2*)(Bm + (size_t)base0 * NST) + hf * 3;
    float2 b01c = Bp[0], b23c = Bp[1], b45c = Bp[2];
#pragma unroll
    for (int j = 0; j < LC; j++) {
        unsigned dun = 0;
        float2 b01n, b23n, b45n;
        if (j + 1 < LC) {
            dun = dlu[(size_t)(base0 + j + 1) * DIN + d];
            const float2* Bq = (const float2*)(Bm + (size_t)(base0 + j + 1) * NST) + hf * 3;
            b01n = Bq[0]; b23n = Bq[1]; b45n = Bq[2];
        }
        float dl = __uint_as_float(duc << 16);
        float uu = __uint_as_float(duc & 0xFFFF0000u);
        float du = dl * uu;
        S += dl;
        h0 = fmaf(__expf(dl * a01.x), h0, du * b01c.x);
        h1 = fmaf(__expf(dl * a01.y), h1, du * b01c.y);
        h2 = fmaf(__expf(dl * a23.x), h2, du * b23c.x);
        h3 = fmaf(__expf(dl * a23.y), h3, du * b23c.y);
        h4 = fmaf(__expf(dl * a45.x), h4, du * b45c.x);
        h5 = fmaf(__expf(dl * a45.y), h5, du * b45c.y);
        duc = dun; b01c = b01n; b23c = b23n; b45c = b45n;
    }
    if (hf == 0) S_arr[c * DIN + d] = S;
    float2* hp = (float2*)(Hb + (size_t)(c * DIN + d) * NST + hf * 6);
    hp[0] = make_float2(h0, h1); hp[1] = make_float2(h2, h3); hp[2] = make_float2(h4, h5);
}

// ---------------------------------------------------------------- chunk-level scan; Hb[c] <- h_in (batched)
__global__ void k_chunkscan(float* __restrict__ pb, const float* __restrict__ wf) {
    int idx = blockIdx.x * 256 + threadIdx.x;     // 2 * 3840
    int b = idx / (DIN * NST);
    int r = idx - b * (DIN * NST);
    int d = r / NST, n = r % NST;
    float* base = pb + (size_t)b * PBSZ;
    const float* S_arr = base + PB_S;
    float* Hb = base + PB_HB;
    float A = wf[OFF_AF + d * NST + n];
    float h = 0.f;
    float sc[16], qc[16];
#pragma unroll
    for (int j = 0; j < 16; j++) {
        sc[j] = S_arr[j * DIN + d];
        qc[j] = Hb[(size_t)(j * DIN + d) * NST + n];
    }
    for (int c0 = 0; c0 < NC; c0 += 16) {
        float sn[16], qn[16];
        if (c0 + 16 < NC) {
#pragma unroll
            for (int j = 0; j < 16; j++) {
                sn[j] = S_arr[(c0 + 16 + j) * DIN + d];
                qn[j] = Hb[(size_t)((c0 + 16 + j) * DIN + d) * NST + n];
            }
        }
#pragma unroll
        for (int j = 0; j < 16; j++) {
            Hb[(size_t)((c0 + j) * DIN + d) * NST + n] = h;
            h = fmaf(__expf(A * sc[j]), h, qc[j]);
        }
#pragma unroll
        for (int j = 0; j < 16; j++) { sc[j] = sn[j]; qc[j] = qn[j]; }
    }
}

// ---------------------------------------------------------------- scan pass 2 -> yb bf16 (batched)
__global__ __launch_bounds__(256) void k_scan2(float* __restrict__ pb, const float* __restrict__ wf) {
    int idx = blockIdx.x * 256 + threadIdx.x;     // 614400
    int b = idx / (NC * DIN * 4);
    int r = idx - b * (NC * DIN * 4);
    int hf = r & 3;
    int d  = (r >> 2) % DIN;
    int c  = r / (DIN * 4);
    float* base = pb + (size_t)b * PBSZ;
    const unsigned* dlu = (const unsigned*)(base + PB_DLU);
    const float* Bm = base + PB_BM;
    const float* Cm = base + PB_CM;
    const float* Hb = base + PB_HB;
    const __hip_bfloat16* zs = (const __hip_bfloat16*)(base + PB_ZS);
    __hip_bfloat16* yb = (__hip_bfloat16*)(base + PB_YB);

    const float2* Ap = (const float2*)(wf + OFF_AF + d * NST + hf * 6);
    float2 a01 = Ap[0], a23 = Ap[1], a45 = Ap[2];
    const float2* Hp = (const float2*)(Hb + (size_t)(c * DIN + d) * NST + hf * 6);
    float2 h01 = Hp[0], h23 = Hp[1], h45 = Hp[2];
    float h0 = h01.x, h1 = h01.y, h2 = h23.x, h3 = h23.y, h4 = h45.x, h5 = h45.y;
    float Dd = wf[OFF_DW + d];
    int base0 = c * LC;
    unsigned duc = dlu[(size_t)base0 * DIN + d];
    const float2* Bp = (const float2*)(Bm + (size_t)base0 * NST) + hf * 3;
    const float2* Cp = (const float2*)(Cm + (size_t)base0 * NST) + hf * 3;
    float2 b01c = Bp[0], b23c = Bp[1], b45c = Bp[2];
    float2 c01c = Cp[0], c23c = Cp[1], c45c = Cp[2];
#pragma unroll
    for (int j = 0; j < LC; j++) {
        unsigned dun = 0;
        float2 b01n, b23n, b45n, c01n, c23n, c45n;
        if (j + 1 < LC) {
            dun = dlu[(size_t)(base0 + j + 1) * DIN + d];
            const float2* Bq = (const float2*)(Bm + (size_t)(base0 + j + 1) * NST) + hf * 3;
            const float2* Cq = (const float2*)(Cm + (size_t)(base0 + j + 1) * NST) + hf * 3;
            b01n = Bq[0]; b23n = Bq[1]; b45n = Bq[2];
            c01n = Cq[0]; c23n = Cq[1]; c45n = Cq[2];
        }
        float dl = __uint_as_float(duc << 16);
        float uu = __uint_as_float(duc & 0xFFFF0000u);
        float du = dl * uu;
        float y;
        h0 = fmaf(__expf(dl * a01.x), h0, du * b01c.x); y = h0 * c01c.x;
        h1 = fmaf(__expf(dl * a01.y), h1, du * b01c.y); y = fmaf(h1, c01c.y, y);
        h2 = fmaf(__expf(dl * a23.x), h2, du * b23c.x); y = fmaf(h2, c23c.x, y);
        h3 = fmaf(__expf(dl * a23.y), h3, du * b23c.y); y = fmaf(h3, c23c.y, y);
        h4 = fmaf(__expf(dl * a45.x), h4, du * b45c.x); y = fmaf(h4, c45c.x, y);
        h5 = fmaf(__expf(dl * a45.y), h5, du * b45c.y); y = fmaf(h5, c45c.y, y);
        y += __shfl_xor(y, 1);
        y += __shfl_xor(y, 2);
        if (hf == 0) {
            size_t zo = (size_t)(base0 + j) * DIN + d;
            yb[zo] = __float2bfloat16((y + uu * Dd) * __bfloat162float(zs[zo]));
        }
        duc = dun; b01c = b01n; b23c = b23n; b45c = b45n; c01c = c01n; c23c = c23n; c45c = c45n;
    }
}

// ----------------------------------------------------------------
extern "C" void kernel_launch(void* const* d_in, const int* in_sizes, int n_in,
                              void* d_out, int out_size, void* d_ws, size_t ws_size,
                              hipStream_t stream) {
    const void* x    = d_in[0];
    const void* nw   = d_in[1];
    const void* nb_  = d_in[2];
    const void* Win  = d_in[3];
    const void* cw   = d_in[4];
    const void* cb   = d_in[5];
    const void* Wx   = d_in[6];
    const void* Wdt  = d_in[7];
    const void* bdt  = d_in[8];
    const void* Alog = d_in[9];
    const void* Dw   = d_in[10];
    const void* Wout = d_in[11];
    const void* fw   = d_in[12];
    const void* sc   = d_in[13];
    (void)in_sizes; (void)n_in; (void)out_size; (void)ws_size;

    float* wf = (float*)d_ws;
    float* pb = wf + WF_TOTAL;

    k_cvtw<<<365, 256, 0, stream>>>(nw, nb_, Win, cw, cb, Wx, Wdt, bdt, Alog, Dw, Wout, fw, sc, wf);
    k_wcomb<<<160, 256, 0, stream>>>(wf);
    k_wg<<<320, 256, 0, stream>>>(wf);
    k_cvtb<<<640, 256, 0, stream>>>(wf);

    k_trans<<<dim3(HW / 32, C_ / 32, 2), dim3(32, 32), 0, stream>>>(x, nw, pb);
    k_ln<<<dim3(3600, 1, 2), 256, 0, stream>>>(pb, wf);
    k_mgemm<128, 0><<<dim3(225, 5, 2), 128, 0, stream>>>(pb, wf, nullptr, nullptr, nullptr);
    k_conv<<<18000, 256, 0, stream>>>(pb, wf);
    k_mgemm<160, 1><<<dim3(225, 4, 2), 128, 0, stream>>>(pb, wf, nullptr, nullptr, nullptr);
    k_scan1<<<2400, 256, 0, stream>>>(pb, wf);
    k_chunkscan<<<30, 256, 0, stream>>>(pb, wf);
    k_scan2<<<2400, 256, 0, stream>>>(pb, wf);
    k_mgemm<640, 2><<<dim3(225, 2, 2), 128, 0, stream>>>(pb, wf, x, nw, d_out);
}